// Round 1
// baseline (628.027 us; speedup 1.0000x reference)
//
#include <hip/hip_runtime.h>
#include <hip/hip_bf16.h>

// Problem constants
#define BSZ   8192
#define DIN   4096
#define RNK   2048
#define UNT   4096

typedef __attribute__((ext_vector_type(4))) float  f32x4;
typedef __attribute__((ext_vector_type(8))) float  f32x8;
typedef __attribute__((ext_vector_type(8))) short  s16x8;
typedef __attribute__((ext_vector_type(8))) unsigned short u16x8;

typedef unsigned short u16;

__device__ __forceinline__ u16 f2bf(float f) {
    unsigned int u = __builtin_bit_cast(unsigned int, f);
    // round-to-nearest-even (finite inputs only)
    return (u16)((u + 0x7fffu + ((u >> 16) & 1u)) >> 16);
}

// ---------------- fp32 -> bf16 elementwise convert (8 elems/thread) -------
__global__ void cvt_bf16_kernel(const float* __restrict__ x,
                                u16* __restrict__ y, int n8) {
    int i = blockIdx.x * blockDim.x + threadIdx.x;
    if (i >= n8) return;
    f32x8 v = ((const f32x8*)x)[i];
    u16x8 o;
#pragma unroll
    for (int j = 0; j < 8; ++j) o[j] = f2bf(v[j]);
    ((u16x8*)y)[i] = o;
}

// ------------- U transpose + fold S:  Ut[r][k] = bf16(U[k][r] * S[r]) -----
__global__ void transpose_scale_kernel(const float* __restrict__ U,
                                       const float* __restrict__ S,
                                       u16* __restrict__ Ut) {
    __shared__ float tile[32][33];
    const int r0 = blockIdx.x * 32;   // RANK tile
    const int k0 = blockIdx.y * 32;   // D_IN tile
    const int tx = threadIdx.x;       // 0..31
    const int ty = threadIdx.y;       // 0..7
#pragma unroll
    for (int i = 0; i < 32; i += 8)
        tile[ty + i][tx] = U[(size_t)(k0 + ty + i) * RNK + r0 + tx];
    __syncthreads();
#pragma unroll
    for (int i = 0; i < 32; i += 8) {
        int r = r0 + ty + i;
        Ut[(size_t)r * DIN + k0 + tx] = f2bf(tile[tx][ty + i] * S[r]);
    }
}

// ---------------- async global->LDS, 16B per lane -------------------------
__device__ __forceinline__ void glds16(const void* g, void* l) {
    __builtin_amdgcn_global_load_lds(
        (const __attribute__((address_space(1))) unsigned int*)g,
        (__attribute__((address_space(3))) unsigned int*)l,
        16, 0, 0);
}

// ---------------- 128x128 tile bf16 GEMM, C = A @ B^T ---------------------
// A: [M][K] bf16 bits, Bt: [N][K] bf16 bits (row-major; row n = output col n)
// RELU_BIAS: C is float [M][N], C = relu(acc + bias[col]); else C is bf16.
template <int K, bool RELU_BIAS>
__global__ __launch_bounds__(256) void gemm_bt(
    const u16* __restrict__ A, const u16* __restrict__ Bt,
    void* __restrict__ C, const float* __restrict__ bias, int N) {
    __shared__ u16 As[128 * 32];
    __shared__ u16 Bs[128 * 32];

    const int t    = threadIdx.x;
    const int wave = t >> 6;
    const int lane = t & 63;

    const int rowBase = blockIdx.y * 128;
    const int colBase = blockIdx.x * 128;

    // staging: thread t loads 8 contiguous bf16 (16B); LDS offset = t*16 (+4096)
    const int sRow = t >> 2;          // 0..63
    const int sCol = (t & 3) * 8;     // 0,8,16,24
    const u16* aG = A  + (size_t)(rowBase + sRow) * K + sCol;
    const u16* bG = Bt + (size_t)(colBase + sRow) * K + sCol;
    u16* aL0 = &As[sRow * 32 + sCol];
    u16* aL1 = &As[(sRow + 64) * 32 + sCol];
    u16* bL0 = &Bs[sRow * 32 + sCol];
    u16* bL1 = &Bs[(sRow + 64) * 32 + sCol];

    // wave subtile (2x2 of 64x64); fragment indices
    const int wm = (wave >> 1) * 64;
    const int wn = (wave & 1) * 64;
    const int fr = lane & 15;
    const int fk = (lane >> 4) * 8;

    const u16* aF = &As[(wm + fr) * 32 + fk];
    const u16* bF = &Bs[(wn + fr) * 32 + fk];

    f32x4 acc[4][4] = {};

    for (int k0 = 0; k0 < K; k0 += 32) {
        __syncthreads();                 // previous tile's LDS reads done
        glds16(aG + k0,            aL0);
        glds16(aG + (size_t)64 * K + k0, aL1);
        glds16(bG + k0,            bL0);
        glds16(bG + (size_t)64 * K + k0, bL1);
        __syncthreads();                 // drains vmcnt: staging visible

        s16x8 af[4], bf[4];
#pragma unroll
        for (int i = 0; i < 4; ++i) af[i] = *(const s16x8*)(aF + i * 16 * 32);
#pragma unroll
        for (int j = 0; j < 4; ++j) bf[j] = *(const s16x8*)(bF + j * 16 * 32);
#pragma unroll
        for (int i = 0; i < 4; ++i)
#pragma unroll
            for (int j = 0; j < 4; ++j)
                acc[i][j] = __builtin_amdgcn_mfma_f32_16x16x32_bf16(
                    af[i], bf[j], acc[i][j], 0, 0, 0);
    }

    // epilogue: C/D layout col = lane&15, row = (lane>>4)*4 + reg
    const int cRow = rowBase + wm + (lane >> 4) * 4;
    const int cCol = colBase + wn + fr;
    if (RELU_BIAS) {
        float* Cf = (float*)C;
#pragma unroll
        for (int j = 0; j < 4; ++j) {
            const int col = cCol + j * 16;
            const float bv = bias[col];
#pragma unroll
            for (int i = 0; i < 4; ++i) {
#pragma unroll
                for (int r = 0; r < 4; ++r) {
                    float v = acc[i][j][r] + bv;
                    Cf[(size_t)(cRow + i * 16 + r) * N + col] = v > 0.f ? v : 0.f;
                }
            }
        }
    } else {
        u16* Cb = (u16*)C;
#pragma unroll
        for (int j = 0; j < 4; ++j) {
            const int col = cCol + j * 16;
#pragma unroll
            for (int i = 0; i < 4; ++i) {
#pragma unroll
                for (int r = 0; r < 4; ++r)
                    Cb[(size_t)(cRow + i * 16 + r) * N + col] = f2bf(acc[i][j][r]);
            }
        }
    }
}

extern "C" void kernel_launch(void* const* d_in, const int* in_sizes, int n_in,
                              void* d_out, int out_size, void* d_ws, size_t ws_size,
                              hipStream_t stream) {
    const float* X    = (const float*)d_in[0];   // [B, D_IN]
    const float* U    = (const float*)d_in[1];   // [D_IN, RANK]
    const float* S    = (const float*)d_in[2];   // [RANK]
    const float* V    = (const float*)d_in[3];   // [UNITS, RANK]
    const float* bias = (const float*)d_in[4];   // [UNITS]
    float* out = (float*)d_out;                  // [B, UNITS] fp32

    char* ws = (char*)d_ws;
    u16* Xb  = (u16*)ws;                                  // 8192*4096 bf16 = 64 MB
    u16* Utb = (u16*)(ws + ((size_t)64 << 20));           // 2048*4096 bf16 = 16 MB
    u16* Vb  = (u16*)(ws + ((size_t)80 << 20));           // 4096*2048 bf16 = 16 MB
    u16* Hb  = (u16*)(ws + ((size_t)96 << 20));           // 8192*2048 bf16 = 32 MB

    // 1) convert X -> bf16
    {
        int n8 = (BSZ * DIN) / 8;
        cvt_bf16_kernel<<<n8 / 256, 256, 0, stream>>>(X, Xb, n8);
    }
    // 2) Ut = (U * S)^T in bf16
    {
        dim3 grid(RNK / 32, DIN / 32), block(32, 8);
        transpose_scale_kernel<<<grid, block, 0, stream>>>(U, S, Utb);
    }
    // 3) convert V -> bf16 (already [UNITS][RANK] = B^T layout for GEMM2)
    {
        int n8 = (UNT * RNK) / 8;
        cvt_bf16_kernel<<<n8 / 256, 256, 0, stream>>>(V, Vb, n8);
    }
    // 4) H = X @ (U*S)   [8192 x 2048], K=4096, bf16 out
    {
        dim3 grid(RNK / 128, BSZ / 128);
        gemm_bt<DIN, false><<<grid, 256, 0, stream>>>(Xb, Utb, Hb, nullptr, RNK);
    }
    // 5) out = relu(H @ V^T + bias)   [8192 x 4096], K=2048, fp32 out
    {
        dim3 grid(UNT / 128, BSZ / 128);
        gemm_bt<RNK, true><<<grid, 256, 0, stream>>>(Hb, Vb, out, bias, UNT);
    }
}

// Round 2
// 572.200 us; speedup vs baseline: 1.0976x; 1.0976x over previous
//
#include <hip/hip_runtime.h>
#include <hip/hip_bf16.h>

// Problem constants
#define BSZ   8192
#define DIN   4096
#define RNK   2048
#define UNT   4096

typedef __attribute__((ext_vector_type(4))) float  f32x4;
typedef __attribute__((ext_vector_type(8))) float  f32x8;
typedef __attribute__((ext_vector_type(8))) short  s16x8;
typedef __attribute__((ext_vector_type(8))) unsigned short u16x8;

typedef unsigned short u16;

__device__ __forceinline__ u16 f2bf(float f) {
    unsigned int u = __builtin_bit_cast(unsigned int, f);
    // round-to-nearest-even (finite inputs only)
    return (u16)((u + 0x7fffu + ((u >> 16) & 1u)) >> 16);
}

// ---------------- fp32 -> bf16 elementwise convert (8 elems/thread) -------
__global__ void cvt_bf16_kernel(const float* __restrict__ x,
                                u16* __restrict__ y, int n8) {
    int i = blockIdx.x * blockDim.x + threadIdx.x;
    if (i >= n8) return;
    f32x8 v = ((const f32x8*)x)[i];
    u16x8 o;
#pragma unroll
    for (int j = 0; j < 8; ++j) o[j] = f2bf(v[j]);
    ((u16x8*)y)[i] = o;
}

// ------------- U transpose + fold S:  Ut[r][k] = bf16(U[k][r] * S[r]) -----
__global__ void transpose_scale_kernel(const float* __restrict__ U,
                                       const float* __restrict__ S,
                                       u16* __restrict__ Ut) {
    __shared__ float tile[32][33];
    const int r0 = blockIdx.x * 32;   // RANK tile
    const int k0 = blockIdx.y * 32;   // D_IN tile
    const int tx = threadIdx.x;       // 0..31
    const int ty = threadIdx.y;       // 0..7
#pragma unroll
    for (int i = 0; i < 32; i += 8)
        tile[ty + i][tx] = U[(size_t)(k0 + ty + i) * RNK + r0 + tx];
    __syncthreads();
#pragma unroll
    for (int i = 0; i < 32; i += 8) {
        int r = r0 + ty + i;
        Ut[(size_t)r * DIN + k0 + tx] = f2bf(tile[tx][ty + i] * S[r]);
    }
}

// ---------------- async global->LDS, 16B per lane -------------------------
__device__ __forceinline__ void glds16(const void* g, void* l) {
    __builtin_amdgcn_global_load_lds(
        (const __attribute__((address_space(1))) unsigned int*)g,
        (__attribute__((address_space(3))) unsigned int*)l,
        16, 0, 0);
}

// ---------------- 128x128 tile bf16 GEMM, C = A @ B^T ---------------------
// A: [M][K] bf16 bits, Bt: [N][K] bf16 bits (row-major; row n = output col n)
// BK=64, staged as two 128x32 LDS chunks per matrix (keeps the conflict-free-ish
// chunk layout AND the lane-contiguous global_load_lds destination rule;
// a 128x64 monolith would put every row at bank 0).
// RELU_BIAS: C is float [M][N], C = relu(acc + bias[col]); else C is bf16.
template <int K, bool RELU_BIAS>
__global__ __launch_bounds__(256) void gemm_bt(
    const u16* __restrict__ A, const u16* __restrict__ Bt,
    void* __restrict__ C, const float* __restrict__ bias, int N) {
    __shared__ u16 As[2][128 * 32];
    __shared__ u16 Bs[2][128 * 32];

    const int t    = threadIdx.x;
    const int wave = t >> 6;
    const int lane = t & 63;

    const int rowBase = blockIdx.y * 128;
    const int colBase = blockIdx.x * 128;

    // staging: thread t loads 8 contiguous bf16 (16B); LDS offset = t*16 bytes
    const int sRow = t >> 2;          // 0..63
    const int sCol = (t & 3) * 8;     // 0,8,16,24
    const u16* aG = A  + (size_t)(rowBase + sRow) * K + sCol;
    const u16* bG = Bt + (size_t)(colBase + sRow) * K + sCol;
    const int lo = sRow * 32 + sCol;          // rows 0..63 chunk offset
    const int hi = (sRow + 64) * 32 + sCol;   // rows 64..127

    // wave subtile (2x2 of 64x64); fragment indices
    const int wm = (wave >> 1) * 64;
    const int wn = (wave & 1) * 64;
    const int fr = lane & 15;
    const int fk = (lane >> 4) * 8;

    const int fOff = (wm + fr) * 32 + fk;   // A-side fragment base (per chunk)
    const int gOff = (wn + fr) * 32 + fk;   // B-side fragment base (per chunk)

    f32x4 acc[4][4] = {};

    for (int k0 = 0; k0 < K; k0 += 64) {
        __syncthreads();                 // previous tile's LDS reads done
        // 8 loads in flight per drain: 2 chunks x (A,B) x (rows lo, rows hi)
        glds16(aG + k0,                       &As[0][lo]);
        glds16(aG + (size_t)64 * K + k0,      &As[0][hi]);
        glds16(aG + k0 + 32,                  &As[1][lo]);
        glds16(aG + (size_t)64 * K + k0 + 32, &As[1][hi]);
        glds16(bG + k0,                       &Bs[0][lo]);
        glds16(bG + (size_t)64 * K + k0,      &Bs[0][hi]);
        glds16(bG + k0 + 32,                  &Bs[1][lo]);
        glds16(bG + (size_t)64 * K + k0 + 32, &Bs[1][hi]);
        __syncthreads();                 // drains vmcnt: staging visible

#pragma unroll
        for (int h = 0; h < 2; ++h) {
            const u16* aF = &As[h][fOff];
            const u16* bF = &Bs[h][gOff];
            s16x8 af[4], bf[4];
#pragma unroll
            for (int i = 0; i < 4; ++i) af[i] = *(const s16x8*)(aF + i * 16 * 32);
#pragma unroll
            for (int j = 0; j < 4; ++j) bf[j] = *(const s16x8*)(bF + j * 16 * 32);
#pragma unroll
            for (int i = 0; i < 4; ++i)
#pragma unroll
                for (int j = 0; j < 4; ++j)
                    acc[i][j] = __builtin_amdgcn_mfma_f32_16x16x32_bf16(
                        af[i], bf[j], acc[i][j], 0, 0, 0);
        }
    }

    // epilogue: C/D layout col = lane&15, row = (lane>>4)*4 + reg
    const int cRow = rowBase + wm + (lane >> 4) * 4;
    const int cCol = colBase + wn + fr;
    if (RELU_BIAS) {
        float* Cf = (float*)C;
#pragma unroll
        for (int j = 0; j < 4; ++j) {
            const int col = cCol + j * 16;
            const float bv = bias[col];
#pragma unroll
            for (int i = 0; i < 4; ++i) {
#pragma unroll
                for (int r = 0; r < 4; ++r) {
                    float v = acc[i][j][r] + bv;
                    Cf[(size_t)(cRow + i * 16 + r) * N + col] = v > 0.f ? v : 0.f;
                }
            }
        }
    } else {
        u16* Cb = (u16*)C;
#pragma unroll
        for (int j = 0; j < 4; ++j) {
            const int col = cCol + j * 16;
#pragma unroll
            for (int i = 0; i < 4; ++i) {
#pragma unroll
                for (int r = 0; r < 4; ++r)
                    Cb[(size_t)(cRow + i * 16 + r) * N + col] = f2bf(acc[i][j][r]);
            }
        }
    }
}

extern "C" void kernel_launch(void* const* d_in, const int* in_sizes, int n_in,
                              void* d_out, int out_size, void* d_ws, size_t ws_size,
                              hipStream_t stream) {
    const float* X    = (const float*)d_in[0];   // [B, D_IN]
    const float* U    = (const float*)d_in[1];   // [D_IN, RANK]
    const float* S    = (const float*)d_in[2];   // [RANK]
    const float* V    = (const float*)d_in[3];   // [UNITS, RANK]
    const float* bias = (const float*)d_in[4];   // [UNITS]
    float* out = (float*)d_out;                  // [B, UNITS] fp32

    char* ws = (char*)d_ws;
    u16* Xb  = (u16*)ws;                                  // 8192*4096 bf16 = 64 MB
    u16* Utb = (u16*)(ws + ((size_t)64 << 20));           // 2048*4096 bf16 = 16 MB
    u16* Vb  = (u16*)(ws + ((size_t)80 << 20));           // 4096*2048 bf16 = 16 MB
    u16* Hb  = (u16*)(ws + ((size_t)96 << 20));           // 8192*2048 bf16 = 32 MB

    // 1) convert X -> bf16
    {
        int n8 = (BSZ * DIN) / 8;
        cvt_bf16_kernel<<<n8 / 256, 256, 0, stream>>>(X, Xb, n8);
    }
    // 2) Ut = (U * S)^T in bf16
    {
        dim3 grid(RNK / 32, DIN / 32), block(32, 8);
        transpose_scale_kernel<<<grid, block, 0, stream>>>(U, S, Utb);
    }
    // 3) convert V -> bf16 (already [UNITS][RANK] = B^T layout for GEMM2)
    {
        int n8 = (UNT * RNK) / 8;
        cvt_bf16_kernel<<<n8 / 256, 256, 0, stream>>>(V, Vb, n8);
    }
    // 4) H = X @ (U*S)   [8192 x 2048], K=4096, bf16 out
    {
        dim3 grid(RNK / 128, BSZ / 128);
        gemm_bt<DIN, false><<<grid, 256, 0, stream>>>(Xb, Utb, Hb, nullptr, RNK);
    }
    // 5) out = relu(H @ V^T + bias)   [8192 x 4096], K=2048, fp32 out
    {
        dim3 grid(UNT / 128, BSZ / 128);
        gemm_bt<RNK, true><<<grid, 256, 0, stream>>>(Hb, Vb, out, bias, UNT);
    }
}